// Round 14
// baseline (153.461 us; speedup 1.0000x reference)
//
#include <hip/hip_runtime.h>

// N=50000, E=800000, CUR=128, HID=96, OUT=128 (derived at runtime)

typedef __attribute__((ext_vector_type(8))) short bf16x8;   // MFMA A/B frag
typedef __attribute__((ext_vector_type(4))) float f32x4;    // MFMA C/D frag

// ---------------------------------------------------------------------------
__device__ __forceinline__ float bf2f(unsigned short u) {
    return __uint_as_float(((unsigned)u) << 16);
}
__device__ __forceinline__ unsigned short f2bf(float f) {
    unsigned u = __float_as_uint(f);
    return (unsigned short)((u + 0x7FFFu + ((u >> 16) & 1u)) >> 16);
}

__device__ __forceinline__ int edge_src(const int* ei, int e, int E, int flag) {
    return flag ? ei[2 * e] : ei[e];
}
__device__ __forceinline__ int edge_dst(const int* ei, int e, int E, int flag) {
    return flag ? ei[2 * (E + e)] : ei[E + e];
}

// Device-scope spin barrier (all gridDim blocks co-resident; ctr pre-zeroed).
__device__ __forceinline__ void gbar(int* ctr, int nb) {
    __syncthreads();
    if (threadIdx.x == 0) {
        __threadfence();
        atomicAdd(ctr, 1);
        while (__hip_atomic_load(ctr, __ATOMIC_RELAXED, __HIP_MEMORY_SCOPE_AGENT) < nb) {}
    }
    __syncthreads();
    __threadfence();
}

// ---------------------------------------------------------------------------
// K-prep: block 0 = int64/int32 flag detect; blocks 1.. = weight repack +
// zero cntS (8N ints) + barrier ctr (contiguous, int4 stores).
__global__ void k_wprep(const unsigned* __restrict__ eiu,
                        const float* __restrict__ Wl, const float* __restrict__ Wr,
                        const float* __restrict__ Wa, const float* __restrict__ Va,
                        const float* __restrict__ preW,
                        unsigned short* __restrict__ Wf_s,
                        unsigned short* __restrict__ Wf_a,
                        unsigned short* __restrict__ Wfp,
                        int* __restrict__ flag,
                        int4* __restrict__ cnt4, int nz4) {
    if (blockIdx.x == 0) {  // flag: high words of first 1024 row-0 entries
        __shared__ int bad;
        if (threadIdx.x == 0) bad = 0;
        __syncthreads();
        int nb = 0;
#pragma unroll
        for (int q = 0; q < 4; q++) {
            unsigned w = eiu[2 * (threadIdx.x * 4 + q) + 1];
            if (w != 0) nb++;
        }
        if (nb) atomicAdd(&bad, nb);
        __syncthreads();
        if (threadIdx.x == 0) *flag = (bad == 0) ? 1 : 0;  // 1 => int64
        return;
    }
    int tid = (blockIdx.x - 1) * blockDim.x + threadIdx.x;
    if (tid < 6144) {  // main weights: 2 mats x 6 ksteps x 4 g x 128 j
        int mat = tid / 3072, rem = tid % 3072;
        int kstep = rem / 512, rem2 = rem % 512;
        int g = rem2 / 128, j = rem2 % 128;
        int k0 = kstep * 32 + g * 8;
        const float* Wtop = mat ? Wa : Wl;
        const float* Wbot = mat ? Va : Wr;
        unsigned short* dst = (mat ? Wf_a : Wf_s) + (((size_t)(kstep * 4 + g) * 128 + j) * 8);
#pragma unroll
        for (int kk = 0; kk < 8; kk++) {
            int k = k0 + kk;
            float v = (k < 96) ? Wtop[k * 128 + j] : Wbot[(k - 96) * 128 + j];
            dst[kk] = f2bf(v);
        }
    } else if (tid < 7680) {  // pre weights: 4 ksteps x 4 g x 96 j
        int rem = tid - 6144;
        int kstep = rem / 384, rem2 = rem % 384;
        int g = rem2 / 96, j = rem2 % 96;
        int k0 = kstep * 32 + g * 8;
        unsigned short* dst = Wfp + (((size_t)(kstep * 4 + g) * 96 + j) * 8);
#pragma unroll
        for (int kk = 0; kk < 8; kk++) dst[kk] = f2bf(preW[(k0 + kk) * 96 + j]);
    } else if (tid >= 8192 && tid < 8192 + nz4) {  // zero cntS + barrier
        cnt4[tid - 8192] = make_int4(0, 0, 0, 0);
    }
}

// ---------------------------------------------------------------------------
// K1: MERGED. Blocks [0,xhBlocks): xh = x @ pre_W + pre_b (MFMA) + his=x copy.
// Blocks [xhBlocks,...): edge rank/count, 1 edge/thread (R8-proven config),
// 8-way sharded cnt.
__global__ __launch_bounds__(256) void k_xh_count(
    const float* __restrict__ x, const unsigned short* __restrict__ Wfp,
    const float* __restrict__ b, unsigned short* __restrict__ xhbf,
    float* __restrict__ out0, int N, int xhBlocks,
    const int* __restrict__ ei, int* __restrict__ cntS, int* __restrict__ pos,
    int E, const int* __restrict__ flagp) {
    __shared__ unsigned short X[64][136];  // 136 shorts = 17x16B (odd) => 2-way max
    if (blockIdx.x >= xhBlocks) {  // ---- count part ----
        int e = (blockIdx.x - xhBlocks) * 256 + threadIdx.x;
        if (e < E) {
            int flag = *flagp;
            int d = edge_dst(ei, e, E, flag);
            int shard = blockIdx.x & 7;
            int lp = atomicAdd(&cntS[(size_t)shard * N + d], 1);
            pos[e] = (lp << 3) | shard;
        }
        return;
    }
    // ---- xh part ----
    int t = threadIdx.x;
    int nb = blockIdx.x * 64;
    for (int u = t; u < 2048; u += 256) {
        int row = u >> 5, q = u & 31;
        long gn = nb + row;
        float4 v = make_float4(0.f, 0.f, 0.f, 0.f);
        if (gn < N) {
            v = ((const float4*)(x + gn * 128))[q];
            ((float4*)(out0 + gn * 128))[q] = v;  // his = x
        }
        unsigned short* p = &X[row][q * 4];
        p[0] = f2bf(v.x); p[1] = f2bf(v.y); p[2] = f2bf(v.z); p[3] = f2bf(v.w);
    }
    __syncthreads();
    int lane = t & 63, w = t >> 6;
    int lr = lane & 15, lg = lane >> 4;
    bf16x8 a[4];
#pragma unroll
    for (int ks = 0; ks < 4; ks++)
        a[ks] = *(const bf16x8*)&X[w * 16 + lr][ks * 32 + lg * 8];
    for (int jt = 0; jt < 6; jt++) {
        f32x4 acc = {0.f, 0.f, 0.f, 0.f};
#pragma unroll
        for (int ks = 0; ks < 4; ks++) {
            bf16x8 bf = *(const bf16x8*)(Wfp + (((size_t)(ks * 4 + lg) * 96 + jt * 16 + lr) * 8));
            acc = __builtin_amdgcn_mfma_f32_16x16x32_bf16(a[ks], bf, acc, 0, 0, 0);
        }
        int h = jt * 16 + lr;
        float bb = b[h];
#pragma unroll
        for (int r = 0; r < 4; r++) {
            long n = nb + w * 16 + lg * 4 + r;
            if (n < N) xhbf[n * 96 + h] = f2bf(acc[r] + bb);
        }
    }
}

// ---------------------------------------------------------------------------
// K-scan: FUSED per-block scan + global base. One spin barrier; both phases
// are O(1)-per-node at 196 co-resident blocks (safe, unlike R10's fill phase).
__global__ __launch_bounds__(256) void k_scan(
    const int* __restrict__ cntS, int* __restrict__ sdelta,
    int* __restrict__ offs, int* __restrict__ bsum, int* __restrict__ bar, int N) {
    __shared__ int sh[256];
    int t = threadIdx.x;
    int n = blockIdx.x * 256 + t;
    int total = 0;
    if (n < N) {
        int run = 0;
#pragma unroll
        for (int s = 0; s < 8; s++) {
            sdelta[(size_t)s * N + n] = run;
            run += cntS[(size_t)s * N + n];
        }
        total = run;
    }
    sh[t] = total;
    __syncthreads();
    for (int off = 1; off < 256; off <<= 1) {
        int add = (t >= off) ? sh[t - off] : 0;
        __syncthreads();
        sh[t] += add;
        __syncthreads();
    }
    int incl = sh[t];
    if (t == 255) bsum[blockIdx.x] = sh[255];
    gbar(bar, gridDim.x);
    // base = sum of bsum[0..blockIdx)
    sh[t] = (t < (int)blockIdx.x) ? bsum[t] : 0;
    __syncthreads();
    for (int s = 128; s > 0; s >>= 1) {
        if (t < s) sh[t] += sh[t + s];
        __syncthreads();
    }
    int base = sh[0];
    if (n < N) offs[n + 1] = base + incl;
    if (blockIdx.x == 0 && t == 0) offs[0] = 0;
}

// ---------------------------------------------------------------------------
// K4: fill CSR, no atomics: idx = offs[d] + sdelta[shard][d] + localpos.
// esw packs {src, weight-bits} -> ONE 8B scattered store per edge.
__global__ void k_fill(const int* __restrict__ ei, const float* __restrict__ ew,
                       const int* __restrict__ offs, const int* __restrict__ sdelta,
                       const int* __restrict__ pos, int2* __restrict__ esw,
                       int E, int N, const int* __restrict__ flagp) {
    int e = blockIdx.x * blockDim.x + threadIdx.x;
    if (e >= E) return;
    int flag = *flagp;
    int s = edge_src(ei, e, E, flag);
    int d = edge_dst(ei, e, E, flag);
    int pp = pos[e];
    int shard = pp & 7, lp = pp >> 3;
    int idx = offs[d] + sdelta[(size_t)shard * N + d] + lp;
    esw[idx] = make_int2(s, __float_as_int(ew[e]));
}

// ---------------------------------------------------------------------------
// K4b: per-dst degree from CSR segment -> dinv, minv.
__global__ void k_degcsr(const int2* __restrict__ esw, const int* __restrict__ offs,
                         float* __restrict__ dinv, float* __restrict__ minv, int N) {
    int n = blockIdx.x * blockDim.x + threadIdx.x;
    if (n >= N) return;
    int beg = offs[n], end = offs[n + 1];
    float dg = 0.f;
    for (int e = beg; e < end; e++) dg += __int_as_float(esw[e].y);
    dinv[n] = dg > 0.f ? rsqrtf(fmaxf(dg, 1e-30f)) : 0.f;
    minv[n] = 1.f / fmaxf((float)(end - beg), 1.f);
}

// ---------------------------------------------------------------------------
// K5: gather per dst (1 wave/dst). 8-ladder SOFTWARE-PIPELINED: group g+1's
// metadata (esw, dinv) loads issue while group g's row loads are in flight,
// removing the md->dv->row serial chain from the steady-state critical path.
__global__ __launch_bounds__(256) void k_gather(
    const int2* __restrict__ esw, const unsigned short* __restrict__ xhbf,
    const int* __restrict__ offs, const float* __restrict__ dinv,
    const float* __restrict__ minv, unsigned short* __restrict__ meanbf,
    unsigned short* __restrict__ propbf, int N) {
    int lane = threadIdx.x & 63;
    int d = __builtin_amdgcn_readfirstlane(blockIdx.x * 4 + (threadIdx.x >> 6));
    if (d >= N) return;
    int beg = offs[d], end = offs[d + 1];
    bool act = lane < 48;
    int col = 2 * lane;
    float s0 = 0.f, s1 = 0.f, a0 = 0.f, a1 = 0.f;
    int e = beg;
    if (e + 8 <= end) {
        int2 md[8]; float dv[8];
#pragma unroll
        for (int q = 0; q < 8; q++) md[q] = esw[e + q];
#pragma unroll
        for (int q = 0; q < 8; q++) dv[q] = dinv[md[q].x];
        for (;;) {
            bool more = (e + 16 <= end);
            unsigned v[8];
#pragma unroll
            for (int q = 0; q < 8; q++)
                v[q] = act ? *(const unsigned*)(xhbf + (size_t)md[q].x * 96 + col) : 0u;
            int2 mdn[8]; float dvn[8];
            if (more) {
#pragma unroll
                for (int q = 0; q < 8; q++) mdn[q] = esw[e + 8 + q];
#pragma unroll
                for (int q = 0; q < 8; q++) dvn[q] = dinv[mdn[q].x];
            }
#pragma unroll
            for (int q = 0; q < 8; q++) {
                float x0 = bf2f((unsigned short)(v[q] & 0xffff));
                float x1 = bf2f((unsigned short)(v[q] >> 16));
                float w2 = __int_as_float(md[q].y), dw = dv[q] * w2;
                s0 += w2 * x0; s1 += w2 * x1;
                a0 += dw * x0; a1 += dw * x1;
            }
            e += 8;
            if (!more) break;
#pragma unroll
            for (int q = 0; q < 8; q++) { md[q] = mdn[q]; dv[q] = dvn[q]; }
        }
    }
    for (; e + 4 <= end; e += 4) {
        int2 md[4]; float dv[4]; unsigned v[4];
#pragma unroll
        for (int q = 0; q < 4; q++) md[q] = esw[e + q];
#pragma unroll
        for (int q = 0; q < 4; q++) dv[q] = dinv[md[q].x];
#pragma unroll
        for (int q = 0; q < 4; q++)
            v[q] = act ? *(const unsigned*)(xhbf + (size_t)md[q].x * 96 + col) : 0u;
#pragma unroll
        for (int q = 0; q < 4; q++) {
            float x0 = bf2f((unsigned short)(v[q] & 0xffff));
            float x1 = bf2f((unsigned short)(v[q] >> 16));
            float w2 = __int_as_float(md[q].y), dw = dv[q] * w2;
            s0 += w2 * x0; s1 += w2 * x1;
            a0 += dw * x0; a1 += dw * x1;
        }
    }
    for (; e < end; e++) {
        int2 md = esw[e];
        float w2 = __int_as_float(md.y);
        float ds = dinv[md.x];
        if (act) {
            unsigned v = *(const unsigned*)(xhbf + (size_t)md.x * 96 + col);
            float x0 = bf2f((unsigned short)(v & 0xffff));
            float x1 = bf2f((unsigned short)(v >> 16));
            s0 += w2 * x0; s1 += w2 * x1;
            a0 += ds * w2 * x0; a1 += ds * w2 * x1;
        }
    }
    if (act) {
        float mi = minv[d], di = dinv[d];
        unsigned mo = (unsigned)f2bf(s0 * mi) | ((unsigned)f2bf(s1 * mi) << 16);
        unsigned po = (unsigned)f2bf(a0 * di) | ((unsigned)f2bf(a1 * di) << 16);
        *(unsigned*)(meanbf + (size_t)d * 96 + col) = mo;
        *(unsigned*)(propbf + (size_t)d * 96 + col) = po;
    }
}

// ---------------------------------------------------------------------------
// K6: epilogue via two K=192 MFMA GEMMs (see R3). 64 nodes/block.
__global__ __launch_bounds__(256) void k_out(
    const unsigned short* __restrict__ meanbf, const unsigned short* __restrict__ propbf,
    const unsigned short* __restrict__ xhbf, const unsigned short* __restrict__ Wf_s,
    const unsigned short* __restrict__ Wf_a, const float* __restrict__ bl,
    const float* __restrict__ ba, float* __restrict__ out, int N) {
    __shared__ unsigned short A[3][64][104];  // 104 shorts = 13x16B (odd) => 2-way max
    int t = threadIdx.x;
    int nb = blockIdx.x * 64;
    for (int u = t; u < 2304; u += 256) {
        int arr = u / 768, rem = u - arr * 768;
        int row = rem / 12, c = rem - row * 12;
        long gn = nb + row;
        const unsigned short* src = (arr == 0) ? meanbf : (arr == 1) ? propbf : xhbf;
        float4 v = (gn < N) ? *(const float4*)(src + gn * 96 + c * 8)
                            : make_float4(0.f, 0.f, 0.f, 0.f);
        *(float4*)&A[arr][row][c * 8] = v;
    }
    __syncthreads();
    int lane = t & 63, w = t >> 6;
    int lr = lane & 15, lg = lane >> 4;
    bf16x8 am[3], ap[3], ax[3];
#pragma unroll
    for (int ks = 0; ks < 3; ks++) {
        int row = w * 16 + lr, kc = ks * 32 + lg * 8;
        am[ks] = *(const bf16x8*)&A[0][row][kc];
        ap[ks] = *(const bf16x8*)&A[1][row][kc];
        ax[ks] = *(const bf16x8*)&A[2][row][kc];
    }
    for (int jt = 0; jt < 8; jt++) {
        f32x4 accS = {0.f, 0.f, 0.f, 0.f};
        f32x4 accA = {0.f, 0.f, 0.f, 0.f};
#pragma unroll
        for (int ks = 0; ks < 3; ks++) {
            size_t boffS = ((size_t)(ks * 4 + lg) * 128 + jt * 16 + lr) * 8;
            size_t boffS2 = ((size_t)((ks + 3) * 4 + lg) * 128 + jt * 16 + lr) * 8;
            bf16x8 b0 = *(const bf16x8*)(Wf_s + boffS);
            bf16x8 b1 = *(const bf16x8*)(Wf_s + boffS2);
            bf16x8 b2 = *(const bf16x8*)(Wf_a + boffS);
            bf16x8 b3 = *(const bf16x8*)(Wf_a + boffS2);
            accS = __builtin_amdgcn_mfma_f32_16x16x32_bf16(am[ks], b0, accS, 0, 0, 0);
            accS = __builtin_amdgcn_mfma_f32_16x16x32_bf16(ax[ks], b1, accS, 0, 0, 0);
            accA = __builtin_amdgcn_mfma_f32_16x16x32_bf16(ap[ks], b2, accA, 0, 0, 0);
            accA = __builtin_amdgcn_mfma_f32_16x16x32_bf16(ax[ks], b3, accA, 0, 0, 0);
        }
        int j = jt * 16 + lr;
        float blj = bl[j], baj = ba[j];
#pragma unroll
        for (int r = 0; r < 4; r++) {
            long n = nb + w * 16 + lg * 4 + r;
            if (n < N) {
                float os = accS[r] + blj;
                float oa = fmaxf(accA[r] + baj, 0.f);
                float o1 = os > 0.f ? os : 0.01f * os;
                float o2 = oa > 0.f ? oa : 0.01f * oa;
                out[n * 128 + j] = fmaxf(o1 + o2, 0.f);
            }
        }
    }
}

// ---------------------------------------------------------------------------
extern "C" void kernel_launch(void* const* d_in, const int* in_sizes, int n_in,
                              void* d_out, int out_size, void* d_ws, size_t ws_size,
                              hipStream_t stream) {
    const float* x    = (const float*)d_in[1];
    const int*   ei   = (const int*)d_in[2];
    const float* ew   = (const float*)d_in[3];
    const float* preW = (const float*)d_in[4];
    const float* preb = (const float*)d_in[5];
    const float* Wl   = (const float*)d_in[6];
    const float* bl   = (const float*)d_in[7];
    const float* Wr   = (const float*)d_in[8];
    const float* Wa   = (const float*)d_in[9];
    const float* Va   = (const float*)d_in[10];
    const float* ba   = (const float*)d_in[11];

    const int N = in_sizes[1] / 128;
    const int E = in_sizes[3];
    const int NB = (N + 255) / 256;  // 196 (<=256 required by k_scan; co-resident)

    // ws layout
    char* w = (char*)d_ws;
    unsigned short* xhbf   = (unsigned short*)w; w += (size_t)N * 96 * 2;
    unsigned short* meanbf = (unsigned short*)w; w += (size_t)N * 96 * 2;
    unsigned short* propbf = (unsigned short*)w; w += (size_t)N * 96 * 2;
    unsigned short* Wf_s   = (unsigned short*)w; w += (size_t)6 * 4 * 128 * 8 * 2;
    unsigned short* Wf_a   = (unsigned short*)w; w += (size_t)6 * 4 * 128 * 8 * 2;
    unsigned short* Wfp    = (unsigned short*)w; w += (size_t)4 * 4 * 96 * 8 * 2;
    int2*  esw    = (int2*)w;  w += (size_t)E * 8;     // packed {src, w-bits}
    int*   pos    = (int*)w;   w += (size_t)E * 4;
    int*   cntS   = (int*)w;   w += (size_t)8 * N * 4;  // 8 shards (zeroed)
    int*   bar    = (int*)w;   w += 4 * 4;               // scan barrier (zeroed)
    int*   sdelta = (int*)w;   w += (size_t)8 * N * 4;
    float* dinv   = (float*)w; w += (size_t)N * 4;
    float* minv   = (float*)w; w += (size_t)N * 4;
    int*   offs   = (int*)w;   w += (size_t)(N + 1) * 4;
    int*   bsum   = (int*)w;   w += 256 * 4;
    int*   flag   = (int*)w;

    const int nz4 = (8 * N + 4 + 3) / 4;  // int4 chunks: cntS + bar
    const int wprep_blocks = 1 + (8192 + nz4 + 255) / 256;
    const int xhBlocks = (N + 63) / 64;
    const int cntBlocks = (E + 255) / 256;  // 1 edge/thread (R8 config)

    k_wprep<<<wprep_blocks, 256, 0, stream>>>((const unsigned*)ei, Wl, Wr, Wa, Va,
                                              preW, Wf_s, Wf_a, Wfp, flag,
                                              (int4*)cntS, nz4);
    k_xh_count<<<xhBlocks + cntBlocks, 256, 0, stream>>>(
        x, Wfp, preb, xhbf, (float*)d_out, N, xhBlocks, ei, cntS, pos, E, flag);
    k_scan<<<NB, 256, 0, stream>>>(cntS, sdelta, offs, bsum, bar, N);
    k_fill<<<(E + 255) / 256, 256, 0, stream>>>(ei, ew, offs, sdelta, pos, esw,
                                                E, N, flag);
    k_degcsr<<<NB, 256, 0, stream>>>(esw, offs, dinv, minv, N);
    k_gather<<<(N + 3) / 4, 256, 0, stream>>>(esw, xhbf, offs, dinv,
                                              minv, meanbf, propbf, N);
    k_out<<<(N + 63) / 64, 256, 0, stream>>>(meanbf, propbf, xhbf, Wf_s, Wf_a,
                                             bl, ba, (float*)d_out + (size_t)N * 128, N);
}

// Round 15
// 137.871 us; speedup vs baseline: 1.1131x; 1.1131x over previous
//
#include <hip/hip_runtime.h>

// N=50000, E=800000, CUR=128, HID=96, OUT=128 (derived at runtime)
// R15 = exact revert to R13 (best-known: 137.9 us). No new changes.

typedef __attribute__((ext_vector_type(8))) short bf16x8;   // MFMA A/B frag
typedef __attribute__((ext_vector_type(4))) float f32x4;    // MFMA C/D frag

// ---------------------------------------------------------------------------
__device__ __forceinline__ float bf2f(unsigned short u) {
    return __uint_as_float(((unsigned)u) << 16);
}
__device__ __forceinline__ unsigned short f2bf(float f) {
    unsigned u = __float_as_uint(f);
    return (unsigned short)((u + 0x7FFFu + ((u >> 16) & 1u)) >> 16);
}

__device__ __forceinline__ int edge_src(const int* ei, int e, int E, int flag) {
    return flag ? ei[2 * e] : ei[e];
}
__device__ __forceinline__ int edge_dst(const int* ei, int e, int E, int flag) {
    return flag ? ei[2 * (E + e)] : ei[E + e];
}

// ---------------------------------------------------------------------------
// K-prep: block 0 = int64/int32 flag detect; blocks 1.. = weight repack +
// zero cntS (8N ints, int4 stores).
__global__ void k_wprep(const unsigned* __restrict__ eiu,
                        const float* __restrict__ Wl, const float* __restrict__ Wr,
                        const float* __restrict__ Wa, const float* __restrict__ Va,
                        const float* __restrict__ preW,
                        unsigned short* __restrict__ Wf_s,
                        unsigned short* __restrict__ Wf_a,
                        unsigned short* __restrict__ Wfp,
                        int* __restrict__ flag,
                        int4* __restrict__ cnt4, int nz4) {
    if (blockIdx.x == 0) {  // flag: high words of first 1024 row-0 entries
        __shared__ int bad;
        if (threadIdx.x == 0) bad = 0;
        __syncthreads();
        int nb = 0;
#pragma unroll
        for (int q = 0; q < 4; q++) {
            unsigned w = eiu[2 * (threadIdx.x * 4 + q) + 1];
            if (w != 0) nb++;
        }
        if (nb) atomicAdd(&bad, nb);
        __syncthreads();
        if (threadIdx.x == 0) *flag = (bad == 0) ? 1 : 0;  // 1 => int64
        return;
    }
    int tid = (blockIdx.x - 1) * blockDim.x + threadIdx.x;
    if (tid < 6144) {  // main weights: 2 mats x 6 ksteps x 4 g x 128 j
        int mat = tid / 3072, rem = tid % 3072;
        int kstep = rem / 512, rem2 = rem % 512;
        int g = rem2 / 128, j = rem2 % 128;
        int k0 = kstep * 32 + g * 8;
        const float* Wtop = mat ? Wa : Wl;
        const float* Wbot = mat ? Va : Wr;
        unsigned short* dst = (mat ? Wf_a : Wf_s) + (((size_t)(kstep * 4 + g) * 128 + j) * 8);
#pragma unroll
        for (int kk = 0; kk < 8; kk++) {
            int k = k0 + kk;
            float v = (k < 96) ? Wtop[k * 128 + j] : Wbot[(k - 96) * 128 + j];
            dst[kk] = f2bf(v);
        }
    } else if (tid < 7680) {  // pre weights: 4 ksteps x 4 g x 96 j
        int rem = tid - 6144;
        int kstep = rem / 384, rem2 = rem % 384;
        int g = rem2 / 96, j = rem2 % 96;
        int k0 = kstep * 32 + g * 8;
        unsigned short* dst = Wfp + (((size_t)(kstep * 4 + g) * 96 + j) * 8);
#pragma unroll
        for (int kk = 0; kk < 8; kk++) dst[kk] = f2bf(preW[(k0 + kk) * 96 + j]);
    } else if (tid >= 8192 && tid < 8192 + nz4) {  // zero cntS
        cnt4[tid - 8192] = make_int4(0, 0, 0, 0);
    }
}

// ---------------------------------------------------------------------------
// K1: MERGED. Blocks [0,xhBlocks): xh = x @ pre_W + pre_b (MFMA) + his=x copy.
// Blocks [xhBlocks,...): edge rank/count, 1 edge/thread (R8-proven config),
// 8-way sharded cnt.
__global__ __launch_bounds__(256) void k_xh_count(
    const float* __restrict__ x, const unsigned short* __restrict__ Wfp,
    const float* __restrict__ b, unsigned short* __restrict__ xhbf,
    float* __restrict__ out0, int N, int xhBlocks,
    const int* __restrict__ ei, int* __restrict__ cntS, int* __restrict__ pos,
    int E, const int* __restrict__ flagp) {
    __shared__ unsigned short X[64][136];  // 136 shorts = 17x16B (odd) => 2-way max
    if (blockIdx.x >= xhBlocks) {  // ---- count part ----
        int e = (blockIdx.x - xhBlocks) * 256 + threadIdx.x;
        if (e < E) {
            int flag = *flagp;
            int d = edge_dst(ei, e, E, flag);
            int shard = blockIdx.x & 7;
            int lp = atomicAdd(&cntS[(size_t)shard * N + d], 1);
            pos[e] = (lp << 3) | shard;
        }
        return;
    }
    // ---- xh part ----
    int t = threadIdx.x;
    int nb = blockIdx.x * 64;
    for (int u = t; u < 2048; u += 256) {
        int row = u >> 5, q = u & 31;
        long gn = nb + row;
        float4 v = make_float4(0.f, 0.f, 0.f, 0.f);
        if (gn < N) {
            v = ((const float4*)(x + gn * 128))[q];
            ((float4*)(out0 + gn * 128))[q] = v;  // his = x
        }
        unsigned short* p = &X[row][q * 4];
        p[0] = f2bf(v.x); p[1] = f2bf(v.y); p[2] = f2bf(v.z); p[3] = f2bf(v.w);
    }
    __syncthreads();
    int lane = t & 63, w = t >> 6;
    int lr = lane & 15, lg = lane >> 4;
    bf16x8 a[4];
#pragma unroll
    for (int ks = 0; ks < 4; ks++)
        a[ks] = *(const bf16x8*)&X[w * 16 + lr][ks * 32 + lg * 8];
    for (int jt = 0; jt < 6; jt++) {
        f32x4 acc = {0.f, 0.f, 0.f, 0.f};
#pragma unroll
        for (int ks = 0; ks < 4; ks++) {
            bf16x8 bf = *(const bf16x8*)(Wfp + (((size_t)(ks * 4 + lg) * 96 + jt * 16 + lr) * 8));
            acc = __builtin_amdgcn_mfma_f32_16x16x32_bf16(a[ks], bf, acc, 0, 0, 0);
        }
        int h = jt * 16 + lr;
        float bb = b[h];
#pragma unroll
        for (int r = 0; r < 4; r++) {
            long n = nb + w * 16 + lg * 4 + r;
            if (n < N) xhbf[n * 96 + h] = f2bf(acc[r] + bb);
        }
    }
}

// ---------------------------------------------------------------------------
// Scan: per-block inclusive scan of node totals; bsum[b] = raw block total.
__global__ void k_scan_blk(const int* __restrict__ cntS, int* __restrict__ sdelta,
                           int* __restrict__ offs, int* __restrict__ bsum, int N) {
    __shared__ int sh[256];
    int t = threadIdx.x;
    int n = blockIdx.x * 256 + t;
    int total = 0;
    if (n < N) {
        int run = 0;
#pragma unroll
        for (int s = 0; s < 8; s++) {
            sdelta[(size_t)s * N + n] = run;
            run += cntS[(size_t)s * N + n];
        }
        total = run;
    }
    sh[t] = total;
    __syncthreads();
    for (int off = 1; off < 256; off <<= 1) {
        int add = (t >= off) ? sh[t - off] : 0;
        __syncthreads();
        sh[t] += add;
        __syncthreads();
    }
    if (n < N) offs[n + 1] = sh[t];
    if (t == 255) bsum[blockIdx.x] = sh[255];
    if (blockIdx.x == 0 && t == 0) offs[0] = 0;
}

// Scan-add: each block reduces bsum[0..blockIdx) in LDS (NB<=256) -> base.
__global__ void k_scan_add(int* __restrict__ offs, const int* __restrict__ bsum, int N) {
    __shared__ int sh[256];
    int t = threadIdx.x;
    sh[t] = (t < (int)blockIdx.x) ? bsum[t] : 0;
    __syncthreads();
    for (int s = 128; s > 0; s >>= 1) {
        if (t < s) sh[t] += sh[t + s];
        __syncthreads();
    }
    int base = sh[0];
    int n = blockIdx.x * 256 + t;
    if (n < N && blockIdx.x > 0) offs[n + 1] += base;
}

// ---------------------------------------------------------------------------
// K4: fill CSR, no atomics: idx = offs[d] + sdelta[shard][d] + localpos.
// esw packs {src, weight-bits} -> ONE 8B scattered store per edge.
__global__ void k_fill(const int* __restrict__ ei, const float* __restrict__ ew,
                       const int* __restrict__ offs, const int* __restrict__ sdelta,
                       const int* __restrict__ pos, int2* __restrict__ esw,
                       int E, int N, const int* __restrict__ flagp) {
    int e = blockIdx.x * blockDim.x + threadIdx.x;
    if (e >= E) return;
    int flag = *flagp;
    int s = edge_src(ei, e, E, flag);
    int d = edge_dst(ei, e, E, flag);
    int pp = pos[e];
    int shard = pp & 7, lp = pp >> 3;
    int idx = offs[d] + sdelta[(size_t)shard * N + d] + lp;
    esw[idx] = make_int2(s, __float_as_int(ew[e]));
}

// ---------------------------------------------------------------------------
// K4b: per-dst degree from CSR segment -> dinv, minv.
__global__ void k_degcsr(const int2* __restrict__ esw, const int* __restrict__ offs,
                         float* __restrict__ dinv, float* __restrict__ minv, int N) {
    int n = blockIdx.x * blockDim.x + threadIdx.x;
    if (n >= N) return;
    int beg = offs[n], end = offs[n + 1];
    float dg = 0.f;
    for (int e = beg; e < end; e++) dg += __int_as_float(esw[e].y);
    dinv[n] = dg > 0.f ? rsqrtf(fmaxf(dg, 1e-30f)) : 0.f;
    minv[n] = 1.f / fmaxf((float)(end - beg), 1.f);
}

// ---------------------------------------------------------------------------
// K5: gather per dst (1 wave/dst), 8/4/1 unroll ladder (R8-proven).
// Edge metadata one int2 stream (wave-uniform -> s_load bursts).
__global__ __launch_bounds__(256) void k_gather(
    const int2* __restrict__ esw, const unsigned short* __restrict__ xhbf,
    const int* __restrict__ offs, const float* __restrict__ dinv,
    const float* __restrict__ minv, unsigned short* __restrict__ meanbf,
    unsigned short* __restrict__ propbf, int N) {
    int lane = threadIdx.x & 63;
    int d = __builtin_amdgcn_readfirstlane(blockIdx.x * 4 + (threadIdx.x >> 6));
    if (d >= N) return;
    int beg = offs[d], end = offs[d + 1];
    bool act = lane < 48;
    int col = 2 * lane;
    float s0 = 0.f, s1 = 0.f, a0 = 0.f, a1 = 0.f;
    int e = beg;
    for (; e + 8 <= end; e += 8) {
        int2 md[8]; float dv[8]; unsigned v[8];
#pragma unroll
        for (int q = 0; q < 8; q++) md[q] = esw[e + q];
#pragma unroll
        for (int q = 0; q < 8; q++) dv[q] = dinv[md[q].x];
#pragma unroll
        for (int q = 0; q < 8; q++)
            v[q] = act ? *(const unsigned*)(xhbf + (size_t)md[q].x * 96 + col) : 0u;
#pragma unroll
        for (int q = 0; q < 8; q++) {
            float x0 = bf2f((unsigned short)(v[q] & 0xffff));
            float x1 = bf2f((unsigned short)(v[q] >> 16));
            float w2 = __int_as_float(md[q].y), dw = dv[q] * w2;
            s0 += w2 * x0; s1 += w2 * x1;
            a0 += dw * x0; a1 += dw * x1;
        }
    }
    for (; e + 4 <= end; e += 4) {
        int2 md[4]; float dv[4]; unsigned v[4];
#pragma unroll
        for (int q = 0; q < 4; q++) md[q] = esw[e + q];
#pragma unroll
        for (int q = 0; q < 4; q++) dv[q] = dinv[md[q].x];
#pragma unroll
        for (int q = 0; q < 4; q++)
            v[q] = act ? *(const unsigned*)(xhbf + (size_t)md[q].x * 96 + col) : 0u;
#pragma unroll
        for (int q = 0; q < 4; q++) {
            float x0 = bf2f((unsigned short)(v[q] & 0xffff));
            float x1 = bf2f((unsigned short)(v[q] >> 16));
            float w2 = __int_as_float(md[q].y), dw = dv[q] * w2;
            s0 += w2 * x0; s1 += w2 * x1;
            a0 += dw * x0; a1 += dw * x1;
        }
    }
    for (; e < end; e++) {
        int2 md = esw[e];
        float w2 = __int_as_float(md.y);
        float ds = dinv[md.x];
        if (act) {
            unsigned v = *(const unsigned*)(xhbf + (size_t)md.x * 96 + col);
            float x0 = bf2f((unsigned short)(v & 0xffff));
            float x1 = bf2f((unsigned short)(v >> 16));
            s0 += w2 * x0; s1 += w2 * x1;
            a0 += ds * w2 * x0; a1 += ds * w2 * x1;
        }
    }
    if (act) {
        float mi = minv[d], di = dinv[d];
        unsigned mo = (unsigned)f2bf(s0 * mi) | ((unsigned)f2bf(s1 * mi) << 16);
        unsigned po = (unsigned)f2bf(a0 * di) | ((unsigned)f2bf(a1 * di) << 16);
        *(unsigned*)(meanbf + (size_t)d * 96 + col) = mo;
        *(unsigned*)(propbf + (size_t)d * 96 + col) = po;
    }
}

// ---------------------------------------------------------------------------
// K6: epilogue via two K=192 MFMA GEMMs (see R3). 64 nodes/block.
__global__ __launch_bounds__(256) void k_out(
    const unsigned short* __restrict__ meanbf, const unsigned short* __restrict__ propbf,
    const unsigned short* __restrict__ xhbf, const unsigned short* __restrict__ Wf_s,
    const unsigned short* __restrict__ Wf_a, const float* __restrict__ bl,
    const float* __restrict__ ba, float* __restrict__ out, int N) {
    __shared__ unsigned short A[3][64][104];  // 104 shorts = 13x16B (odd) => 2-way max
    int t = threadIdx.x;
    int nb = blockIdx.x * 64;
    for (int u = t; u < 2304; u += 256) {
        int arr = u / 768, rem = u - arr * 768;
        int row = rem / 12, c = rem - row * 12;
        long gn = nb + row;
        const unsigned short* src = (arr == 0) ? meanbf : (arr == 1) ? propbf : xhbf;
        float4 v = (gn < N) ? *(const float4*)(src + gn * 96 + c * 8)
                            : make_float4(0.f, 0.f, 0.f, 0.f);
        *(float4*)&A[arr][row][c * 8] = v;
    }
    __syncthreads();
    int lane = t & 63, w = t >> 6;
    int lr = lane & 15, lg = lane >> 4;
    bf16x8 am[3], ap[3], ax[3];
#pragma unroll
    for (int ks = 0; ks < 3; ks++) {
        int row = w * 16 + lr, kc = ks * 32 + lg * 8;
        am[ks] = *(const bf16x8*)&A[0][row][kc];
        ap[ks] = *(const bf16x8*)&A[1][row][kc];
        ax[ks] = *(const bf16x8*)&A[2][row][kc];
    }
    for (int jt = 0; jt < 8; jt++) {
        f32x4 accS = {0.f, 0.f, 0.f, 0.f};
        f32x4 accA = {0.f, 0.f, 0.f, 0.f};
#pragma unroll
        for (int ks = 0; ks < 3; ks++) {
            size_t boffS = ((size_t)(ks * 4 + lg) * 128 + jt * 16 + lr) * 8;
            size_t boffS2 = ((size_t)((ks + 3) * 4 + lg) * 128 + jt * 16 + lr) * 8;
            bf16x8 b0 = *(const bf16x8*)(Wf_s + boffS);
            bf16x8 b1 = *(const bf16x8*)(Wf_s + boffS2);
            bf16x8 b2 = *(const bf16x8*)(Wf_a + boffS);
            bf16x8 b3 = *(const bf16x8*)(Wf_a + boffS2);
            accS = __builtin_amdgcn_mfma_f32_16x16x32_bf16(am[ks], b0, accS, 0, 0, 0);
            accS = __builtin_amdgcn_mfma_f32_16x16x32_bf16(ax[ks], b1, accS, 0, 0, 0);
            accA = __builtin_amdgcn_mfma_f32_16x16x32_bf16(ap[ks], b2, accA, 0, 0, 0);
            accA = __builtin_amdgcn_mfma_f32_16x16x32_bf16(ax[ks], b3, accA, 0, 0, 0);
        }
        int j = jt * 16 + lr;
        float blj = bl[j], baj = ba[j];
#pragma unroll
        for (int r = 0; r < 4; r++) {
            long n = nb + w * 16 + lg * 4 + r;
            if (n < N) {
                float os = accS[r] + blj;
                float oa = fmaxf(accA[r] + baj, 0.f);
                float o1 = os > 0.f ? os : 0.01f * os;
                float o2 = oa > 0.f ? oa : 0.01f * oa;
                out[n * 128 + j] = fmaxf(o1 + o2, 0.f);
            }
        }
    }
}

// ---------------------------------------------------------------------------
extern "C" void kernel_launch(void* const* d_in, const int* in_sizes, int n_in,
                              void* d_out, int out_size, void* d_ws, size_t ws_size,
                              hipStream_t stream) {
    const float* x    = (const float*)d_in[1];
    const int*   ei   = (const int*)d_in[2];
    const float* ew   = (const float*)d_in[3];
    const float* preW = (const float*)d_in[4];
    const float* preb = (const float*)d_in[5];
    const float* Wl   = (const float*)d_in[6];
    const float* bl   = (const float*)d_in[7];
    const float* Wr   = (const float*)d_in[8];
    const float* Wa   = (const float*)d_in[9];
    const float* Va   = (const float*)d_in[10];
    const float* ba   = (const float*)d_in[11];

    const int N = in_sizes[1] / 128;
    const int E = in_sizes[3];
    const int NB = (N + 255) / 256;  // 196 (<=256 required by k_scan_add)

    // ws layout
    char* w = (char*)d_ws;
    unsigned short* xhbf   = (unsigned short*)w; w += (size_t)N * 96 * 2;
    unsigned short* meanbf = (unsigned short*)w; w += (size_t)N * 96 * 2;
    unsigned short* propbf = (unsigned short*)w; w += (size_t)N * 96 * 2;
    unsigned short* Wf_s   = (unsigned short*)w; w += (size_t)6 * 4 * 128 * 8 * 2;
    unsigned short* Wf_a   = (unsigned short*)w; w += (size_t)6 * 4 * 128 * 8 * 2;
    unsigned short* Wfp    = (unsigned short*)w; w += (size_t)4 * 4 * 96 * 8 * 2;
    int2*  esw    = (int2*)w;  w += (size_t)E * 8;     // packed {src, w-bits}
    int*   pos    = (int*)w;   w += (size_t)E * 4;
    int*   cntS   = (int*)w;   w += (size_t)8 * N * 4;  // 8 shards (zeroed)
    int*   sdelta = (int*)w;   w += (size_t)8 * N * 4;
    float* dinv   = (float*)w; w += (size_t)N * 4;
    float* minv   = (float*)w; w += (size_t)N * 4;
    int*   offs   = (int*)w;   w += (size_t)(N + 1) * 4;
    int*   bsum   = (int*)w;   w += 256 * 4;
    int*   flag   = (int*)w;

    const int nz4 = (8 * N + 3) / 4;  // int4 chunks: cntS
    const int wprep_blocks = 1 + (8192 + nz4 + 255) / 256;
    const int xhBlocks = (N + 63) / 64;
    const int cntBlocks = (E + 255) / 256;  // 1 edge/thread (R8 config)

    k_wprep<<<wprep_blocks, 256, 0, stream>>>((const unsigned*)ei, Wl, Wr, Wa, Va,
                                              preW, Wf_s, Wf_a, Wfp, flag,
                                              (int4*)cntS, nz4);
    k_xh_count<<<xhBlocks + cntBlocks, 256, 0, stream>>>(
        x, Wfp, preb, xhbf, (float*)d_out, N, xhBlocks, ei, cntS, pos, E, flag);
    k_scan_blk<<<NB, 256, 0, stream>>>(cntS, sdelta, offs, bsum, N);
    k_scan_add<<<NB, 256, 0, stream>>>(offs, bsum, N);
    k_fill<<<(E + 255) / 256, 256, 0, stream>>>(ei, ew, offs, sdelta, pos, esw,
                                                E, N, flag);
    k_degcsr<<<NB, 256, 0, stream>>>(esw, offs, dinv, minv, N);
    k_gather<<<(N + 3) / 4, 256, 0, stream>>>(esw, xhbf, offs, dinv,
                                              minv, meanbf, propbf, N);
    k_out<<<(N + 63) / 64, 256, 0, stream>>>(meanbf, propbf, xhbf, Wf_s, Wf_a,
                                             bl, ba, (float*)d_out + (size_t)N * 128, N);
}